// Round 8
// baseline (103.285 us; speedup 1.0000x reference)
//
#include <hip/hip_runtime.h>

#define NUM_CLASSES 80
constexpr int Bn = 8;
constexpr int Gn = 128;
constexpr int An = 131072;

constexpr int TB   = 256;   // threads per block (4 waves)
constexpr int BBLK = 512;   // anchors per block (2 per thread)

// out layout: cls (B,A,80) | reg (B,A,4) | states (B,A)
constexpr size_t CLS_OFF = 0;
constexpr size_t REG_OFF = (size_t)Bn * An * NUM_CLASSES;
constexpr size_t ST_OFF  = REG_OFF + (size_t)Bn * An * 4;

__global__ __launch_bounds__(TB, 4) void targets_kernel(
    const float* __restrict__ ann,      // (B,G,5) x1,y1,x2,y2,label
    const float* __restrict__ anchors,  // (A,4)
    float* __restrict__ out)
{
#pragma clang fp contract(off)
    const int tid  = threadIdx.x;
    const int b    = blockIdx.y;
    const int base = blockIdx.x * BBLK;

    __shared__ float4 sbox[Gn];
    __shared__ float  slabel[Gn];
    __shared__ int    slab[BBLK];

    if (tid < Gn) {
        const float* p = ann + ((size_t)b * Gn + tid) * 5;
        sbox[tid]   = make_float4(p[0], p[1], p[2], p[3]);
        slabel[tid] = p[4];
    }
    __syncthreads();   // staging visible (nothing big outstanding yet)

    float4* cls_blk = reinterpret_cast<float4*>(
        out + CLS_OFF + ((size_t)b * An + base) * NUM_CLASSES);

    // ALL blocks: flood the write queue with data-independent zeros NOW.
    // Store data is a constant-zero register quad -> no vmcnt register
    // recycling hazard; zeros drain (to L2, then HBM) under the compute.
    {
        const float4 z = make_float4(0.f, 0.f, 0.f, 0.f);
        #pragma unroll
        for (int i = 0; i < (BBLK * 20) / TB; ++i)   // 40 float4s/thread
            cls_blk[tid + i * TB] = z;
    }

    // ---- compute: 2 anchors per thread, division-free argmax ----
    const int a = base + tid * 2;
    const float4 av0 = *reinterpret_cast<const float4*>(anchors + (size_t)a * 4);
    const float4 av1 = *reinterpret_cast<const float4*>(anchors + (size_t)a * 4 + 4);

    const float ax1[2] = { av0.x, av1.x };
    const float ay1[2] = { av0.y, av1.y };
    const float ax2[2] = { av0.z, av1.z };
    const float ay2[2] = { av0.w, av1.w };
    float wa[2], ha[2], area_a[2], interB[2], uniB[2];
    int besti[2];
    #pragma unroll
    for (int j = 0; j < 2; ++j) {
        wa[j] = ax2[j] - ax1[j];
        ha[j] = ay2[j] - ay1[j];
        area_a[j] = wa[j] * ha[j];          // ref op order
    }
    {   // g = 0 initializes (argmax starts at index 0)
        const float4 bv = sbox[0];
        const float area_b = (bv.z - bv.x) * (bv.w - bv.y);
        #pragma unroll
        for (int j = 0; j < 2; ++j) {
            float iw = fminf(ax2[j], bv.z) - fmaxf(ax1[j], bv.x);
            iw = fmaxf(iw, 0.0f);
            float ih = fminf(ay2[j], bv.w) - fmaxf(ay1[j], bv.y);
            ih = fmaxf(ih, 0.0f);
            interB[j] = iw * ih;
            uniB[j]   = (area_a[j] + area_b) - interB[j];
            besti[j]  = 0;
        }
    }
    #pragma unroll 2
    for (int g = 1; g < Gn; ++g) {
        const float4 bv = sbox[g];          // broadcast ds_read_b128
        const float area_b = (bv.z - bv.x) * (bv.w - bv.y);  // ref order
        #pragma unroll
        for (int j = 0; j < 2; ++j) {
            float iw = fminf(ax2[j], bv.z) - fmaxf(ax1[j], bv.x);
            iw = fmaxf(iw, 0.0f);
            float ih = fminf(ay2[j], bv.w) - fmaxf(ay1[j], bv.y);
            ih = fmaxf(ih, 0.0f);
            const float inter = iw * ih;
            const float uni = (area_a[j] + area_b) - inter;  // > 0 here
            // iou_g > iou_best  <=>  inter*uniB > interB*uni (both unions > 0)
            const bool upd = (inter * uniB[j]) > (interB[j] * uni);
            interB[j] = upd ? inter : interB[j];
            uniB[j]   = upd ? uni   : uniB[j];
            besti[j]  = upd ? g     : besti[j];
        }
    }

    float st[2];
    #pragma unroll
    for (int j = 0; j < 2; ++j) {
        const float best = interB[j] / fmaxf(uniB[j], 1e-8f);  // exact ref div
        st[j] = (best >= 0.5f) ? 1.0f : ((best < 0.4f) ? 0.0f : -1.0f);
    }
    *reinterpret_cast<float2*>(out + ST_OFF + (size_t)b * An + a) =
        make_float2(st[0], st[1]);

    #pragma unroll
    for (int j = 0; j < 2; ++j) {
        const float4 gt = sbox[besti[j]];
        float4 rv;
        rv.x = ((gt.x - ax1[j]) / wa[j]) / 0.2f;
        rv.y = ((gt.y - ay1[j]) / ha[j]) / 0.2f;
        rv.z = ((gt.z - ax2[j]) / wa[j]) / 0.2f;
        rv.w = ((gt.w - ay2[j]) / ha[j]) / 0.2f;
        *reinterpret_cast<float4*>(out + REG_OFF + ((size_t)b * An + a + j) * 4) = rv;
        slab[tid * 2 + j] = (st[j] == 1.0f) ? (int)slabel[besti[j]] : -1;
    }

    // barrier: slab visible; its vmcnt(0) drain also orders this block's
    // zero-stores (L2-acked) before the patches below.
    __syncthreads();

    // sparse patch: one dword per positive anchor (lines still L2-resident)
    for (int k = tid; k < BBLK; k += TB) {
        const int lab = slab[k];
        if (lab >= 0)
            out[CLS_OFF + ((size_t)b * An + base + k) * NUM_CLASSES + lab] = 1.0f;
    }
}

extern "C" void kernel_launch(void* const* d_in, const int* in_sizes, int n_in,
                              void* d_out, int out_size, void* d_ws, size_t ws_size,
                              hipStream_t stream) {
    const float* ann     = (const float*)d_in[0];   // (8,128,5)
    const float* anchors = (const float*)d_in[1];   // (131072,4)
    float* out = (float*)d_out;

    dim3 grid(An / BBLK, Bn, 1);   // 256 x 8 = 2048 blocks (4 per CU)
    dim3 block(TB, 1, 1);
    targets_kernel<<<grid, block, 0, stream>>>(ann, anchors, out);
}

// Round 9
// 81.337 us; speedup vs baseline: 1.2698x; 1.2698x over previous
//
#include <hip/hip_runtime.h>

#define NUM_CLASSES 80
constexpr int Bn = 8;
constexpr int Gn = 128;
constexpr int An = 131072;

constexpr int TB   = 256;   // threads per block (4 waves)
constexpr int BBLK = 512;   // anchors per block (2 per thread)

constexpr int CH     = 8;                       // interleave chunks
constexpr int ST_PC  = (BBLK * 20) / TB / CH;   // 5 zero-stores per chunk
constexpr int G_PC   = Gn / CH;                 // 16 g-iters per chunk

// out layout: cls (B,A,80) | reg (B,A,4) | states (B,A)
constexpr size_t CLS_OFF = 0;
constexpr size_t REG_OFF = (size_t)Bn * An * NUM_CLASSES;
constexpr size_t ST_OFF  = REG_OFF + (size_t)Bn * An * 4;

__global__ __launch_bounds__(TB, 4) void targets_kernel(
    const float* __restrict__ ann,      // (B,G,5) x1,y1,x2,y2,label
    const float* __restrict__ anchors,  // (A,4)
    float* __restrict__ out)
{
#pragma clang fp contract(off)
    const int tid  = threadIdx.x;
    const int b    = blockIdx.y;
    const int base = blockIdx.x * BBLK;

    __shared__ float4 sbox[Gn];
    __shared__ float  slabel[Gn];
    __shared__ int    slab[BBLK];

    if (tid < Gn) {
        const float* p = ann + ((size_t)b * Gn + tid) * 5;
        sbox[tid]   = make_float4(p[0], p[1], p[2], p[3]);
        slabel[tid] = p[4];
    }

    // anchor loads issued before the barrier (in flight across it)
    const int a = base + tid * 2;
    const float4 av0 = *reinterpret_cast<const float4*>(anchors + (size_t)a * 4);
    const float4 av1 = *reinterpret_cast<const float4*>(anchors + (size_t)a * 4 + 4);

    __syncthreads();   // staging visible

    float4* cls_blk = reinterpret_cast<float4*>(
        out + CLS_OFF + ((size_t)b * An + base) * NUM_CLASSES);
    const float4 z = make_float4(0.f, 0.f, 0.f, 0.f);

    const float ax1[2] = { av0.x, av1.x };
    const float ay1[2] = { av0.y, av1.y };
    const float ax2[2] = { av0.z, av1.z };
    const float ay2[2] = { av0.w, av1.w };
    float wa[2], ha[2], area_a[2], interB[2], uniB[2];
    int besti[2];
    #pragma unroll
    for (int j = 0; j < 2; ++j) {
        wa[j] = ax2[j] - ax1[j];
        ha[j] = ay2[j] - ay1[j];
        area_a[j] = wa[j] * ha[j];      // ref op order
        interB[j] = -1.0f;              // sentinel: g=0 always wins first cmp
        uniB[j]   = 1.0f;
        besti[j]  = 0;
    }

    // ---- interleaved: {5 zero-stores, 16 g-iterations} x 8 chunks ----
    // Zero-stores are data-independent (constant reg quad): they drain on
    // the mem pipe while the g-loop runs on the VALU, per wave, from t=0.
    for (int c = 0; c < CH; ++c) {
        #pragma unroll
        for (int i = 0; i < ST_PC; ++i)
            cls_blk[tid + (c * ST_PC + i) * TB] = z;

        #pragma unroll 4
        for (int gg = 0; gg < G_PC; ++gg) {
            const int g = c * G_PC + gg;
            const float4 bv = sbox[g];            // broadcast ds_read_b128
            const float area_b = (bv.z - bv.x) * (bv.w - bv.y);  // ref order
            #pragma unroll
            for (int j = 0; j < 2; ++j) {
                float iw = fminf(ax2[j], bv.z) - fmaxf(ax1[j], bv.x);
                iw = fmaxf(iw, 0.0f);
                float ih = fminf(ay2[j], bv.w) - fmaxf(ay1[j], bv.y);
                ih = fmaxf(ih, 0.0f);
                const float inter = iw * ih;
                const float uni = (area_a[j] + area_b) - inter;  // > 0
                // iou_g > iou_best <=> inter*uniB > interB*uni (uni>0)
                const bool upd = (inter * uniB[j]) > (interB[j] * uni);
                interB[j] = upd ? inter : interB[j];
                uniB[j]   = upd ? uni   : uniB[j];
                besti[j]  = upd ? g     : besti[j];
            }
        }
    }

    float st[2];
    #pragma unroll
    for (int j = 0; j < 2; ++j) {
        const float best = interB[j] / fmaxf(uniB[j], 1e-8f);  // exact ref div
        st[j] = (best >= 0.5f) ? 1.0f : ((best < 0.4f) ? 0.0f : -1.0f);
    }
    *reinterpret_cast<float2*>(out + ST_OFF + (size_t)b * An + a) =
        make_float2(st[0], st[1]);

    #pragma unroll
    for (int j = 0; j < 2; ++j) {
        const float4 gt = sbox[besti[j]];
        float4 rv;
        rv.x = ((gt.x - ax1[j]) / wa[j]) / 0.2f;
        rv.y = ((gt.y - ay1[j]) / ha[j]) / 0.2f;
        rv.z = ((gt.z - ax2[j]) / wa[j]) / 0.2f;
        rv.w = ((gt.w - ay2[j]) / ha[j]) / 0.2f;
        *reinterpret_cast<float4*>(out + REG_OFF + ((size_t)b * An + a + j) * 4) = rv;
        slab[tid * 2 + j] = (st[j] == 1.0f) ? (int)slabel[besti[j]] : -1;
    }

    // barrier: slab visible; vmcnt(0) drain orders zero-stores before patches
    __syncthreads();

    // sparse patch: one dword per positive anchor (lines still L2-resident)
    for (int k = tid; k < BBLK; k += TB) {
        const int lab = slab[k];
        if (lab >= 0)
            out[CLS_OFF + ((size_t)b * An + base + k) * NUM_CLASSES + lab] = 1.0f;
    }
}

extern "C" void kernel_launch(void* const* d_in, const int* in_sizes, int n_in,
                              void* d_out, int out_size, void* d_ws, size_t ws_size,
                              hipStream_t stream) {
    const float* ann     = (const float*)d_in[0];   // (8,128,5)
    const float* anchors = (const float*)d_in[1];   // (131072,4)
    float* out = (float*)d_out;

    dim3 grid(An / BBLK, Bn, 1);   // 256 x 8 = 2048 blocks
    dim3 block(TB, 1, 1);
    targets_kernel<<<grid, block, 0, stream>>>(ann, anchors, out);
}

// Round 10
// 75.714 us; speedup vs baseline: 1.3642x; 1.0743x over previous
//
#include <hip/hip_runtime.h>

#define NUM_CLASSES 80
constexpr int Bn = 8;
constexpr int Gn = 128;
constexpr int An = 131072;

constexpr int TB   = 256;   // threads per block (4 waves)
constexpr int BBLK = 512;   // anchors per block (2 per thread)

constexpr int CH    = 8;                       // interleave chunks
constexpr int ST_PC = (BBLK * 20) / TB / CH;   // 5 zero-stores per chunk
constexpr int G_PC  = Gn / CH;                 // 16 g-iters per chunk

// out layout: cls (B,A,80) | reg (B,A,4) | states (B,A)
constexpr size_t CLS_OFF = 0;
constexpr size_t REG_OFF = (size_t)Bn * An * NUM_CLASSES;
constexpr size_t ST_OFF  = REG_OFF + (size_t)Bn * An * 4;

__global__ __launch_bounds__(TB, 4) void targets_kernel(
    const float* __restrict__ ann,      // (B,G,5) x1,y1,x2,y2,label
    const float* __restrict__ anchors,  // (A,4)
    float* __restrict__ out)
{
#pragma clang fp contract(off)
    const int tid  = threadIdx.x;
    const int b    = blockIdx.y;
    const int base = blockIdx.x * BBLK;
    const bool compute_first = (blockIdx.x & 1);   // odd: g-iters before stores

    __shared__ float4 sbox[Gn];
    __shared__ float  sarea[Gn];
    __shared__ float  slabel[Gn];
    __shared__ int    slab[BBLK];

    if (tid < Gn) {
        const float* p = ann + ((size_t)b * Gn + tid) * 5;
        const float x1 = p[0], y1 = p[1], x2 = p[2], y2 = p[3];
        sbox[tid]   = make_float4(x1, y1, x2, y2);
        sarea[tid]  = (x2 - x1) * (y2 - y1);   // ref op order
        slabel[tid] = p[4];
    }

    // anchor loads issued before the barrier (in flight across it)
    const int a = base + tid * 2;
    const float4 av0 = *reinterpret_cast<const float4*>(anchors + (size_t)a * 4);
    const float4 av1 = *reinterpret_cast<const float4*>(anchors + (size_t)a * 4 + 4);

    __syncthreads();   // staging visible

    float4* cls_blk = reinterpret_cast<float4*>(
        out + CLS_OFF + ((size_t)b * An + base) * NUM_CLASSES);
    const float4 z = make_float4(0.f, 0.f, 0.f, 0.f);

    const float ax1[2] = { av0.x, av1.x };
    const float ay1[2] = { av0.y, av1.y };
    const float ax2[2] = { av0.z, av1.z };
    const float ay2[2] = { av0.w, av1.w };
    float wa[2], ha[2], area_a[2], interB[2], uniB[2];
    int besti[2];
    #pragma unroll
    for (int j = 0; j < 2; ++j) {
        wa[j] = ax2[j] - ax1[j];
        ha[j] = ay2[j] - ay1[j];
        area_a[j] = wa[j] * ha[j];      // ref op order
        interB[j] = -1.0f;              // sentinel: g=0 wins first compare
        uniB[j]   = 1.0f;
        besti[j]  = 0;
    }

    // one interleave chunk of the division-free argmax
    auto g_chunk = [&](int c) {
        #pragma unroll 4
        for (int gg = 0; gg < G_PC; ++gg) {
            const int g = c * G_PC + gg;
            const float4 bv = sbox[g];        // broadcast ds_read_b128
            const float area_b = sarea[g];    // broadcast ds_read_b32
            #pragma unroll
            for (int j = 0; j < 2; ++j) {
                float iw = fminf(ax2[j], bv.z) - fmaxf(ax1[j], bv.x);
                iw = fmaxf(iw, 0.0f);
                float ih = fminf(ay2[j], bv.w) - fmaxf(ay1[j], bv.y);
                ih = fmaxf(ih, 0.0f);
                const float inter = iw * ih;
                const float uni = (area_a[j] + area_b) - inter;  // > 0
                // iou_g > iou_best <=> inter*uniB > interB*uni (both > 0)
                const bool upd = (inter * uniB[j]) > (interB[j] * uni);
                interB[j] = upd ? inter : interB[j];
                uniB[j]   = upd ? uni   : uniB[j];
                besti[j]  = upd ? g     : besti[j];
            }
        }
    };
    auto store_chunk = [&](int c) {
        #pragma unroll
        for (int i = 0; i < ST_PC; ++i)
            cls_blk[tid + (c * ST_PC + i) * TB] = z;
    };

    // parity-complementary interleave: even blocks store-then-compute,
    // odd blocks compute-then-store -> halves of the device are always in
    // opposite phases, smoothing store demand at CU granularity.
    if (compute_first) {
        for (int c = 0; c < CH; ++c) { g_chunk(c); store_chunk(c); }
    } else {
        for (int c = 0; c < CH; ++c) { store_chunk(c); g_chunk(c); }
    }

    float st[2];
    #pragma unroll
    for (int j = 0; j < 2; ++j) {
        const float best = interB[j] / fmaxf(uniB[j], 1e-8f);  // exact ref div
        st[j] = (best >= 0.5f) ? 1.0f : ((best < 0.4f) ? 0.0f : -1.0f);
    }
    *reinterpret_cast<float2*>(out + ST_OFF + (size_t)b * An + a) =
        make_float2(st[0], st[1]);

    #pragma unroll
    for (int j = 0; j < 2; ++j) {
        const float4 gt = sbox[besti[j]];
        float4 rv;
        rv.x = ((gt.x - ax1[j]) / wa[j]) / 0.2f;
        rv.y = ((gt.y - ay1[j]) / ha[j]) / 0.2f;
        rv.z = ((gt.z - ax2[j]) / wa[j]) / 0.2f;
        rv.w = ((gt.w - ay2[j]) / ha[j]) / 0.2f;
        *reinterpret_cast<float4*>(out + REG_OFF + ((size_t)b * An + a + j) * 4) = rv;
        slab[tid * 2 + j] = (st[j] == 1.0f) ? (int)slabel[besti[j]] : -1;
    }

    // barrier: slab visible; vmcnt(0) drain orders zero-stores before patches
    __syncthreads();

    // sparse patch: one dword per positive anchor (lines still L2-resident)
    for (int k = tid; k < BBLK; k += TB) {
        const int lab = slab[k];
        if (lab >= 0)
            out[CLS_OFF + ((size_t)b * An + base + k) * NUM_CLASSES + lab] = 1.0f;
    }
}

extern "C" void kernel_launch(void* const* d_in, const int* in_sizes, int n_in,
                              void* d_out, int out_size, void* d_ws, size_t ws_size,
                              hipStream_t stream) {
    const float* ann     = (const float*)d_in[0];   // (8,128,5)
    const float* anchors = (const float*)d_in[1];   // (131072,4)
    float* out = (float*)d_out;

    dim3 grid(An / BBLK, Bn, 1);   // 256 x 8 = 2048 blocks
    dim3 block(TB, 1, 1);
    targets_kernel<<<grid, block, 0, stream>>>(ann, anchors, out);
}

// Round 11
// 74.673 us; speedup vs baseline: 1.3832x; 1.0139x over previous
//
#include <hip/hip_runtime.h>

#define NUM_CLASSES 80
constexpr int Bn = 8;
constexpr int Gn = 128;
constexpr int An = 131072;

constexpr int TB   = 256;   // threads per block (4 waves)
constexpr int BBLK = 512;   // anchors per block (2 per thread)

constexpr int CH    = 8;                       // store-burst chunks
constexpr int ST_PC = (BBLK * 20) / TB / CH;   // 5 zero-stores per burst
constexpr int G_PC  = Gn / CH;                 // 16 g-iters per chunk

// out layout: cls (B,A,80) | reg (B,A,4) | states (B,A)
constexpr size_t CLS_OFF = 0;
constexpr size_t REG_OFF = (size_t)Bn * An * NUM_CLASSES;
constexpr size_t ST_OFF  = REG_OFF + (size_t)Bn * An * 4;

__global__ __launch_bounds__(TB, 4) void targets_kernel(
    const float* __restrict__ ann,      // (B,G,5) x1,y1,x2,y2,label
    const float* __restrict__ anchors,  // (A,4)
    float* __restrict__ out)
{
#pragma clang fp contract(off)
    const int tid  = threadIdx.x;
    const int b    = blockIdx.y;
    const int base = blockIdx.x * BBLK;
    // Per-CU phase stagger: the 8 blocks co-resident on a CU are exactly
    // y = 0..7 (same x), so keying the phase on y puts ALL 8 phases on
    // every CU -> store bursts are uniformly spread in time per CU.
    const int p2 = b * 2;               // phase offset in g-iterations (0..14)

    __shared__ float4 sbox[Gn];
    __shared__ float  sarea[Gn];
    __shared__ float  slabel[Gn];
    __shared__ int    slab[BBLK];

    if (tid < Gn) {
        const float* p = ann + ((size_t)b * Gn + tid) * 5;
        const float x1 = p[0], y1 = p[1], x2 = p[2], y2 = p[3];
        sbox[tid]   = make_float4(x1, y1, x2, y2);
        sarea[tid]  = (x2 - x1) * (y2 - y1);   // ref op order
        slabel[tid] = p[4];
    }

    // anchor loads issued before the barrier (in flight across it)
    const int a = base + tid * 2;
    const float4 av0 = *reinterpret_cast<const float4*>(anchors + (size_t)a * 4);
    const float4 av1 = *reinterpret_cast<const float4*>(anchors + (size_t)a * 4 + 4);

    __syncthreads();   // staging visible

    float4* cls_blk = reinterpret_cast<float4*>(
        out + CLS_OFF + ((size_t)b * An + base) * NUM_CLASSES);
    const float4 z = make_float4(0.f, 0.f, 0.f, 0.f);

    const float ax1[2] = { av0.x, av1.x };
    const float ay1[2] = { av0.y, av1.y };
    const float ax2[2] = { av0.z, av1.z };
    const float ay2[2] = { av0.w, av1.w };
    float wa[2], ha[2], area_a[2], interB[2], uniB[2];
    int besti[2];
    #pragma unroll
    for (int j = 0; j < 2; ++j) {
        wa[j] = ax2[j] - ax1[j];
        ha[j] = ay2[j] - ay1[j];
        area_a[j] = wa[j] * ha[j];      // ref op order
        interB[j] = -1.0f;              // sentinel: g=0 wins first compare
        uniB[j]   = 1.0f;
        besti[j]  = 0;
    }

    // one g-iteration of the division-free argmax (g strictly sequential
    // 0..127 across the whole schedule -> tie semantics bit-identical)
    auto g_iter = [&](int g) {
        const float4 bv = sbox[g];        // broadcast ds_read_b128
        const float area_b = sarea[g];    // broadcast ds_read_b32
        #pragma unroll
        for (int j = 0; j < 2; ++j) {
            float iw = fminf(ax2[j], bv.z) - fmaxf(ax1[j], bv.x);
            iw = fmaxf(iw, 0.0f);
            float ih = fminf(ay2[j], bv.w) - fmaxf(ay1[j], bv.y);
            ih = fmaxf(ih, 0.0f);
            const float inter = iw * ih;
            const float uni = (area_a[j] + area_b) - inter;  // > 0
            // iou_g > iou_best <=> inter*uniB > interB*uni (both unions > 0)
            const bool upd = (inter * uniB[j]) > (interB[j] * uni);
            interB[j] = upd ? inter : interB[j];
            uniB[j]   = upd ? uni   : uniB[j];
            besti[j]  = upd ? g     : besti[j];
        }
    };

    // phase-staggered interleave: prologue of 2*y g-iters, then 8 chunks of
    // {5 zero-stores, 16 g-iters} (last chunk short by 2*y).
    int g = 0;
    #pragma unroll 4
    for (; g < p2; ++g) g_iter(g);

    #pragma unroll
    for (int sc = 0; sc < CH; ++sc) {
        #pragma unroll
        for (int i = 0; i < ST_PC; ++i)
            cls_blk[tid + (sc * ST_PC + i) * TB] = z;

        const int gend = (sc == CH - 1) ? Gn : p2 + (sc + 1) * G_PC;
        #pragma unroll 4
        for (; g < gend; ++g) g_iter(g);
    }

    float st[2];
    #pragma unroll
    for (int j = 0; j < 2; ++j) {
        const float best = interB[j] / fmaxf(uniB[j], 1e-8f);  // exact ref div
        st[j] = (best >= 0.5f) ? 1.0f : ((best < 0.4f) ? 0.0f : -1.0f);
    }
    *reinterpret_cast<float2*>(out + ST_OFF + (size_t)b * An + a) =
        make_float2(st[0], st[1]);

    #pragma unroll
    for (int j = 0; j < 2; ++j) {
        const float4 gt = sbox[besti[j]];
        float4 rv;
        rv.x = ((gt.x - ax1[j]) / wa[j]) / 0.2f;
        rv.y = ((gt.y - ay1[j]) / ha[j]) / 0.2f;
        rv.z = ((gt.z - ax2[j]) / wa[j]) / 0.2f;
        rv.w = ((gt.w - ay2[j]) / ha[j]) / 0.2f;
        *reinterpret_cast<float4*>(out + REG_OFF + ((size_t)b * An + a + j) * 4) = rv;
        slab[tid * 2 + j] = (st[j] == 1.0f) ? (int)slabel[besti[j]] : -1;
    }

    // barrier: slab visible; vmcnt(0) drain orders zero-stores before patches
    __syncthreads();

    // sparse patch: one dword per positive anchor
    for (int k = tid; k < BBLK; k += TB) {
        const int lab = slab[k];
        if (lab >= 0)
            out[CLS_OFF + ((size_t)b * An + base + k) * NUM_CLASSES + lab] = 1.0f;
    }
}

extern "C" void kernel_launch(void* const* d_in, const int* in_sizes, int n_in,
                              void* d_out, int out_size, void* d_ws, size_t ws_size,
                              hipStream_t stream) {
    const float* ann     = (const float*)d_in[0];   // (8,128,5)
    const float* anchors = (const float*)d_in[1];   // (131072,4)
    float* out = (float*)d_out;

    dim3 grid(An / BBLK, Bn, 1);   // 256 x 8 = 2048 blocks (8 per CU)
    dim3 block(TB, 1, 1);
    targets_kernel<<<grid, block, 0, stream>>>(ann, anchors, out);
}